// Round 13
// baseline (190.516 us; speedup 1.0000x reference)
//
#include <hip/hip_runtime.h>
#include <hip/hip_fp16.h>

#define R_ 3
#define D_ 7            // 2R+1
#define W_ 49
#define N_ 128
#define K_ 131
#define C_ 21
#define B_ 2
#define NN (N_ * N_)
#define TILE 16                 // 16x16 pixel tile
#define PATCH 22                // TILE + 2R
#define PSH 24                  // patch row stride in h2 elems (4B each)
#define NELEM (PATCH * PATCH)   // 484
#define LDSE (PATCH * PSH + 8)  // 536 h2 elems (spare slot at 532)
#define KC 8
#define KCHUNK ((K_ + KC - 1) / KC)   // 17

typedef __fp16 h2 __attribute__((ext_vector_type(2)));
typedef __fp16 h4 __attribute__((ext_vector_type(4)));

// Affinity: per-pixel 7x7 window softmax per channel, weighted by cp[k].
// Staged value per element: (E', I') = 2^(x-4), 2^(-x-4), x = f*mask*log2e,
// packed f16 (4B). Tap t' = max(Ec'*In', En'*Ic') = 2^-8 * exp(|c-n|): the
// uniform 2^-8 cancels in the softmax, and keeps all f16 intermediates in
// [2^-12, 256] (no overflow even at |c-n|~11). OOB elements stage (0,0)->t'=0.
// THREAD OWNS 2 ADJACENT PIXELS: one 8-element row read (4 x b64, merged to
// 2 x ds_read2_b64) serves both windows -> 15 LDS issues/thread-k vs 50.
// (R9 lesson: every read element here is a true window member of >=1 of the
// two pixels; no phantom taps exist in this layout.)
__global__ __launch_bounds__(128, 2) void rwn_affinity(
    const float* __restrict__ feats,   // [B,K,N,N]
    const int*   __restrict__ mask,    // [B,N,N]
    const float* __restrict__ cp,      // [K]
    float* __restrict__ Aout)          // [B,W,NN] (pre-zeroed)
{
    __shared__ h2 patch[LDSE];

    const int tile = blockIdx.x;           // 0..63 (8x8 tiles of 16x16)
    const int kc   = blockIdx.y;
    const int b    = blockIdx.z;
    const int tr = tile >> 3, tc = tile & 7;
    const int ti0 = tr * TILE, tj0 = tc * TILE;

    const int tid = threadIdx.x;           // 0..127
    const int ti  = tid >> 3;              // 0..15 (pixel row)
    const int tjp = (tid & 7) * 2;         // 0,2,..,14 (first of 2 pixels)
    const int gi = ti0 + ti;
    const int gj0 = tj0 + tjp, gj1 = gj0 + 1;

    // ---- staging setup: thread owns elements tid + r*128, r=0..3 ----
    const float LOG2E = 1.4426950408889634f;
    int   soff[4]; float swt[4]; float ozw[4]; int slds[4];
    #pragma unroll
    for (int r = 0; r < 4; ++r) {
        int e = tid + r * 128;
        bool act = (e < NELEM);
        int pr = e / PATCH, pc = e - pr * PATCH;
        int mi = ti0 + pr - R_, mj = tj0 + pc - R_;
        bool inb = act && mi >= 0 && mi < N_ && mj >= 0 && mj < N_;
        int cmi = mi < 0 ? 0 : (mi > N_ - 1 ? N_ - 1 : mi);
        int cmj = mj < 0 ? 0 : (mj > N_ - 1 ? N_ - 1 : mj);
        soff[r] = cmi * N_ + cmj;
        swt[r]  = inb ? ((float)mask[b * NN + soff[r]] * LOG2E) : 0.f;
        ozw[r]  = inb ? 1.f : 0.f;
        slds[r] = act ? (pr * PSH + pc) : (PATCH * PSH + 4);   // spare slot
    }

    h2 A0[28], A1[28];
    #pragma unroll
    for (int i = 0; i < 28; ++i) { A0[i] = (h2)0.f; A1[i] = (h2)0.f; }

    const int k0 = kc * KCHUNK;
    const int k1 = (k0 + KCHUNK < K_) ? (k0 + KCHUNK) : K_;
    const float* fb = feats + (size_t)b * K_ * NN;

    // zero-init LDS once (pad cols + spare stay 0)
    for (int e = tid; e < LDSE; e += 128) patch[e] = (h2)0.f;

    float pre[4];
    #pragma unroll
    for (int r = 0; r < 4; ++r) pre[r] = fb[(size_t)k0 * NN + soff[r]] * swt[r];

    __syncthreads();

    const int cen = (ti + R_) * PSH + tjp + R_;
    const int rb0 = ti * PSH + tjp;

    for (int k = k0; k < k1; ++k) {
        #pragma unroll
        for (int r = 0; r < 4; ++r) {
            float E = ozw[r] * exp2f(pre[r] - 4.f);
            float I = ozw[r] * exp2f(-pre[r] - 4.f);
            patch[slds[r]] = __builtin_amdgcn_cvt_pkrtz(E, I);
        }
        float nx[4];
        if (k + 1 < k1) {
            const float* fn = fb + (size_t)(k + 1) * NN;
            #pragma unroll
            for (int r = 0; r < 4; ++r) nx[r] = fn[soff[r]] * swt[r];
        } else {
            #pragma unroll
            for (int r = 0; r < 4; ++r) nx[r] = 0.f;
        }
        __syncthreads();

        const h2 c0 = patch[cen];
        const h2 c1 = patch[cen + 1];
        const __fp16 Ec0 = c0.x, Ic0 = c0.y;
        const __fp16 Ec1 = c1.x, Ic1 = c1.y;

        h2 ex0[28], ex1[28];
        h2 ds0 = (h2)0.f, ds1 = (h2)0.f;
        #pragma unroll
        for (int u = 0; u < D_; ++u) {
            const h4* rp = (const h4*)&patch[rb0 + u * PSH];   // 8B-aligned
            const h4 q0 = rp[0], q1 = rp[1], q2 = rp[2], q3 = rp[3];
            __fp16 E[8], I[8];
            E[0]=q0[0]; I[0]=q0[1]; E[1]=q0[2]; I[1]=q0[3];
            E[2]=q1[0]; I[2]=q1[1]; E[3]=q1[2]; I[3]=q1[3];
            E[4]=q2[0]; I[4]=q2[1]; E[5]=q2[2]; I[5]=q2[3];
            E[6]=q3[0]; I[6]=q3[1]; E[7]=q3[2]; I[7]=q3[3];
            __fp16 t0[7], t1[7];
            #pragma unroll
            for (int j = 0; j < 7; ++j) {
                t0[j] = __builtin_fmaxf16((__fp16)(Ec0 * I[j]), (__fp16)(E[j] * Ic0));
                t1[j] = __builtin_fmaxf16((__fp16)(Ec1 * I[j+1]), (__fp16)(E[j+1] * Ic1));
            }
            #pragma unroll
            for (int m = 0; m < 3; ++m) {
                h2 p0 = {t0[2*m], t0[2*m+1]};
                h2 p1 = {t1[2*m], t1[2*m+1]};
                ex0[u*4+m] = p0; ds0 += p0;
                ex1[u*4+m] = p1; ds1 += p1;
            }
            h2 p0t = {t0[6], (__fp16)0.f};
            h2 p1t = {t1[6], (__fp16)0.f};
            ex0[u*4+3] = p0t; ds0 += p0t;
            ex1[u*4+3] = p1t; ds1 += p1t;
        }
        const float cpk = cp[k];
        const float dsum0 = (float)ds0.x + (float)ds0.y;
        const float dsum1 = (float)ds1.x + (float)ds1.y;
        const float sc0 = cpk * __frcp_rn(dsum0);
        const float sc1 = cpk * __frcp_rn(dsum1);
        const h2 s0 = __builtin_amdgcn_cvt_pkrtz(sc0, sc0);
        const h2 s1 = __builtin_amdgcn_cvt_pkrtz(sc1, sc1);
        #pragma unroll
        for (int m = 0; m < 28; ++m) {
            A0[m] = ex0[m] * s0 + A0[m];
            A1[m] = ex1[m] * s1 + A1[m];
        }
        __syncthreads();
        #pragma unroll
        for (int r = 0; r < 4; ++r) pre[r] = nx[r];
    }

    // epilogue: 49 atomics per selected pixel (skip each row's zero filler)
    const int m0 = mask[b * NN + gi * N_ + gj0];
    const int m1 = mask[b * NN + gi * N_ + gj1];
    float* abase = Aout + (size_t)b * W_ * NN + gi * N_;
    if (m0 != 0) {
        float* ab = abase + gj0;
        #pragma unroll
        for (int u = 0; u < D_; ++u) {
            #pragma unroll
            for (int m = 0; m < 4; ++m) {
                const h2 tv = A0[u * 4 + m];
                atomicAdd(ab + (u * D_ + 2 * m) * NN, (float)tv.x);
                if (m < 3)
                    atomicAdd(ab + (u * D_ + 2 * m + 1) * NN, (float)tv.y);
            }
        }
    }
    if (m1 != 0) {
        float* ab = abase + gj1;
        #pragma unroll
        for (int u = 0; u < D_; ++u) {
            #pragma unroll
            for (int m = 0; m < 4; ++m) {
                const h2 tv = A1[u * 4 + m];
                atomicAdd(ab + (u * D_ + 2 * m) * NN, (float)tv.x);
                if (m < 3)
                    atomicAdd(ab + (u * D_ + 2 * m + 1) * NN, (float)tv.y);
            }
        }
    }
}

// Gather (R10 form, best measured): out[b,q,c] = sum_w A[b,w,p]*x2[b,c,p].
// Block = 64 q x 8 w-groups (512 thr); wg owns u=wg (wg=7 idle in taps).
// 21 c-accumulators in registers; LDS reduce over 8 planes; contiguous store.
#define RSTR 22   // LDS reduce stride
__global__ __launch_bounds__(512, 4) void rwn_gather(
    const float* __restrict__ Aarr,  // [B,W,NN]
    const float* __restrict__ x2,    // [B,C,NN]
    float* __restrict__ out)         // [B,NN,C]
{
    __shared__ float red[8 * 64 * RSTR];   // 45056 B

    const int q0 = blockIdx.x * 64;
    const int b  = blockIdx.y;
    const int tid = threadIdx.x;
    const int qh = tid & 63;
    const int wg = tid >> 6;
    const int q = q0 + qh;
    const int i = q >> 7, j = q & (N_ - 1);

    const float* Ab = Aarr + (size_t)b * W_ * NN;
    const float* xb = x2 + (size_t)b * C_ * NN;

    float acc[C_];
    #pragma unroll
    for (int c = 0; c < C_; ++c) acc[c] = 0.f;

    if (wg < D_) {
        const int pi = i - (wg - R_);
        const int cpi = pi < 0 ? 0 : (pi > N_ - 1 ? N_ - 1 : pi);
        const float rv = (pi >= 0 && pi < N_) ? 1.f : 0.f;
        const float* Aw = Ab + (size_t)wg * D_ * NN;
        #pragma unroll
        for (int v = 0; v < D_; ++v) {
            const int pj = j - (v - R_);
            const int cpj = pj < 0 ? 0 : (pj > N_ - 1 ? N_ - 1 : pj);
            const float vv = (pj >= 0 && pj < N_) ? rv : 0.f;
            const int p = cpi * N_ + cpj;
            const float a = vv * Aw[(size_t)v * NN + p];
            #pragma unroll
            for (int c = 0; c < C_; ++c)
                acc[c] += a * xb[(size_t)c * NN + p];
        }
    }

    float* rbase = red + (wg * 64 + qh) * RSTR;
    #pragma unroll
    for (int c = 0; c < C_; ++c) rbase[c] = acc[c];
    __syncthreads();

    float* ob = out + ((size_t)b * NN + q0) * C_;
    for (int e = tid; e < 64 * C_; e += 512) {
        const int qq = e / C_, cc = e - qq * C_;
        const int a = qq * RSTR + cc;
        float s = 0.f;
        #pragma unroll
        for (int pl = 0; pl < 8; ++pl)
            s += red[pl * 64 * RSTR + a];
        ob[e] = s;
    }
}

extern "C" void kernel_launch(void* const* d_in, const int* in_sizes, int n_in,
                              void* d_out, int out_size, void* d_ws, size_t ws_size,
                              hipStream_t stream) {
    const float* feats = (const float*)d_in[0];   // [B,K,N,N]
    const float* x2    = (const float*)d_in[1];   // [B,C,NN]
    const int*   mask  = (const int*)d_in[2];     // [B,N,N]
    const float* cp    = (const float*)d_in[3];   // [K]
    float* out = (float*)d_out;

    float* Aarr = (float*)d_ws;                   // [B,W,NN] fp32
    const size_t Abytes = (size_t)B_ * W_ * NN * sizeof(float);

    (void)hipMemsetAsync(Aarr, 0, Abytes, stream);

    dim3 gridA(64, KC, B_);
    rwn_affinity<<<gridA, 128, 0, stream>>>(feats, mask, cp, Aarr);

    dim3 gridG(NN / 64, B_);
    rwn_gather<<<gridG, 512, 0, stream>>>(Aarr, x2, out);
}

// Round 14
// 159.578 us; speedup vs baseline: 1.1939x; 1.1939x over previous
//
#include <hip/hip_runtime.h>
#include <hip/hip_fp16.h>

#define R_ 3
#define D_ 7            // 2R+1
#define W_ 49
#define N_ 128
#define K_ 131
#define C_ 21
#define B_ 2
#define NN (N_ * N_)
#define TILE 16                 // 16x16 pixel tile
#define PATCH 22                // TILE + 2R
#define PSTR 24                 // LDS row stride (float2 pairs)
#define NELEM (PATCH * PATCH)   // 484 staged elements
#define LDSP (PATCH * PSTR + 8) // 536 pairs (spare write slot at 532)
#define KC 8
#define KCHUNK ((K_ + KC - 1) / KC)   // 17

typedef __fp16 h2 __attribute__((ext_vector_type(2)));

// Affinity with MASK COMPACTION: A[p,:] = 0 for unselected p (the *m factor),
// and ~50% of pixels are unselected -- so only compute softmax taps for
// selected pixels. Ballot/prefix compaction (deterministic, spatial order)
// builds sel[]; thread pairs (h=tid&1 column split, R10's proven f16 tap
// path verbatim: phantom-kill + shfl_xor denominator) process sel[tid>>1]
// and, on rare overflow (nsel>128), sel[(tid>>1)+128] into a second acc.
// Staged (E,Einv)=exp(+/-f*mask) pairs; OOB stages (0,0) -> tap 0.
__global__ __launch_bounds__(256) void rwn_affinity(
    const float* __restrict__ feats,   // [B,K,N,N]
    const int*   __restrict__ mask,    // [B,N,N]
    const float* __restrict__ cp,      // [K]
    float* __restrict__ Aout)          // [B,W,NN] (pre-zeroed)
{
    __shared__ float2 patch2[LDSP];
    __shared__ unsigned char sel[256];
    __shared__ int wq[4];

    const int tile = blockIdx.x;           // 0..63 (8x8 tiles of 16x16)
    const int kc   = blockIdx.y;
    const int b    = blockIdx.z;
    const int tr = tile >> 3, tc = tile & 7;
    const int ti0 = tr * TILE, tj0 = tc * TILE;

    const int tid  = threadIdx.x;
    const int lane = tid & 63, wid = tid >> 6;

    // ---- mask ballot for this thread's tile pixel ----
    const int pti = tid >> 4, ptj = tid & 15;
    const int msel = (mask[b * NN + (ti0 + pti) * N_ + (tj0 + ptj)] != 0) ? 1 : 0;
    unsigned long long bal = __ballot(msel);
    if (lane == 0) wq[wid] = (int)__popcll(bal);

    // ---- staging setup: thread owns elements tid and tid+256 ----
    const float LOG2E = 1.4426950408889634f;
    int soff[2]; float swt[2]; float ozw[2]; int slds[2];
    #pragma unroll
    for (int r = 0; r < 2; ++r) {
        int e = tid + r * 256;
        bool act = (e < NELEM);
        int pr = e / PATCH, pc = e - pr * PATCH;
        int mi = ti0 + pr - R_, mj = tj0 + pc - R_;
        bool inb = act && mi >= 0 && mi < N_ && mj >= 0 && mj < N_;
        int cmi = mi < 0 ? 0 : (mi > N_ - 1 ? N_ - 1 : mi);
        int cmj = mj < 0 ? 0 : (mj > N_ - 1 ? N_ - 1 : mj);
        soff[r] = cmi * N_ + cmj;
        swt[r]  = inb ? ((float)mask[b * NN + soff[r]] * LOG2E) : 0.f;
        ozw[r]  = inb ? 1.f : 0.f;
        slds[r] = act ? (pr * PSTR + pc) : (PATCH * PSTR + 4);  // spare slot
    }

    // zero-init LDS pairs once (pad cols 22,23 + spare stay 0 forever)
    for (int e = tid; e < LDSP; e += 256) patch2[e] = make_float2(0.f, 0.f);

    __syncthreads();   // wq visible, LDS zeroed

    int pre_cnt = 0;
    #pragma unroll
    for (int w = 0; w < 3; ++w) if (w < wid) pre_cnt += wq[w];
    const int nsel = wq[0] + wq[1] + wq[2] + wq[3];
    if (msel)
        sel[pre_cnt + (int)__popcll(bal & ((1ull << lane) - 1ull))] =
            (unsigned char)tid;

    __syncthreads();   // sel[] ready

    const int sA = tid >> 1;
    const int h  = tid & 1;
    const float ph = h ? 0.f : 1.f;        // phantom v=7 killer (h=1,m=1,t1)
    const bool actA = (sA < nsel);         // sA<128 always
    const bool actB = (sA + 128 < nsel);   // rare overflow round
    const int pA = actA ? (int)sel[sA] : 0;
    const int pB = actB ? (int)sel[sA + 128] : 0;
    const int cbA = (pA >> 4) * PSTR + (pA & 15);
    const int cbB = (pB >> 4) * PSTR + (pB & 15);

    h2 Aa[14], Ab[14];
    #pragma unroll
    for (int i = 0; i < 14; ++i) { Aa[i] = (h2)0.f; Ab[i] = (h2)0.f; }

    const int k0 = kc * KCHUNK;
    const int k1 = (k0 + KCHUNK < K_) ? (k0 + KCHUNK) : K_;
    const float* fb = feats + (size_t)b * K_ * NN;

    float pre0 = fb[(size_t)k0 * NN + soff[0]] * swt[0];
    float pre1 = fb[(size_t)k0 * NN + soff[1]] * swt[1];

    for (int k = k0; k < k1; ++k) {
        patch2[slds[0]] = make_float2(ozw[0] * exp2f(pre0), ozw[0] * exp2f(-pre0));
        patch2[slds[1]] = make_float2(ozw[1] * exp2f(pre1), ozw[1] * exp2f(-pre1));
        float n0 = 0.f, n1 = 0.f;
        if (k + 1 < k1) {
            const float* fn = fb + (size_t)(k + 1) * NN;
            n0 = fn[soff[0]] * swt[0];
            n1 = fn[soff[1]] * swt[1];
        }
        __syncthreads();

        const float cpk = cp[k];

        if (actA) {   // uniform across the lane pair -> shfl_xor(1) is safe
            const float2 cpair = patch2[cbA + R_ * PSTR + R_];
            const int bh = cbA + h;
            h2 ex[14];
            float dsum = 0.f;
            #pragma unroll
            for (int u = 0; u < D_; ++u) {
                #pragma unroll
                for (int m = 0; m < 2; ++m) {
                    const float2 np0 = patch2[bh + u * PSTR + 4 * m];
                    const float2 np1 = patch2[bh + u * PSTR + 4 * m + 2];
                    float t0 = fmaxf(cpair.x * np0.y, np0.x * cpair.y);
                    float t1 = fmaxf(cpair.x * np1.y, np1.x * cpair.y);
                    if (m == 1) t1 *= ph;   // phantom v=7 reads REAL data
                    dsum += t0; dsum += t1;
                    ex[u * 2 + m] = __builtin_amdgcn_cvt_pkrtz(t0, t1);
                }
            }
            const float denom = dsum + __shfl_xor(dsum, 1, 64);
            const float scale = cpk * __frcp_rn(denom);
            const h2 s2 = __builtin_amdgcn_cvt_pkrtz(scale, scale);
            #pragma unroll
            for (int m = 0; m < 14; ++m) Aa[m] = ex[m] * s2 + Aa[m];
        }
        if (actB) {
            const float2 cpair = patch2[cbB + R_ * PSTR + R_];
            const int bh = cbB + h;
            h2 ex[14];
            float dsum = 0.f;
            #pragma unroll
            for (int u = 0; u < D_; ++u) {
                #pragma unroll
                for (int m = 0; m < 2; ++m) {
                    const float2 np0 = patch2[bh + u * PSTR + 4 * m];
                    const float2 np1 = patch2[bh + u * PSTR + 4 * m + 2];
                    float t0 = fmaxf(cpair.x * np0.y, np0.x * cpair.y);
                    float t1 = fmaxf(cpair.x * np1.y, np1.x * cpair.y);
                    if (m == 1) t1 *= ph;
                    dsum += t0; dsum += t1;
                    ex[u * 2 + m] = __builtin_amdgcn_cvt_pkrtz(t0, t1);
                }
            }
            const float denom = dsum + __shfl_xor(dsum, 1, 64);
            const float scale = cpk * __frcp_rn(denom);
            const h2 s2 = __builtin_amdgcn_cvt_pkrtz(scale, scale);
            #pragma unroll
            for (int m = 0; m < 14; ++m) Ab[m] = ex[m] * s2 + Ab[m];
        }
        __syncthreads();
        pre0 = n0; pre1 = n1;
    }

    // epilogue: w = u*7 + 4m + h (tv.x) / u*7 + 4m + 2 + h (tv.y, skip phantom)
    if (actA) {
        const int pixg = (ti0 + (pA >> 4)) * N_ + (tj0 + (pA & 15));
        float* ab = Aout + (size_t)b * W_ * NN + h * NN + pixg;
        #pragma unroll
        for (int u = 0; u < D_; ++u) {
            #pragma unroll
            for (int m = 0; m < 2; ++m) {
                const h2 tv = Aa[u * 2 + m];
                atomicAdd(ab + (u * D_ + 4 * m) * NN, (float)tv.x);
                if (h == 0 || m < 1)
                    atomicAdd(ab + (u * D_ + 4 * m + 2) * NN, (float)tv.y);
            }
        }
    }
    if (actB) {
        const int pixg = (ti0 + (pB >> 4)) * N_ + (tj0 + (pB & 15));
        float* ab = Aout + (size_t)b * W_ * NN + h * NN + pixg;
        #pragma unroll
        for (int u = 0; u < D_; ++u) {
            #pragma unroll
            for (int m = 0; m < 2; ++m) {
                const h2 tv = Ab[u * 2 + m];
                atomicAdd(ab + (u * D_ + 4 * m) * NN, (float)tv.x);
                if (h == 0 || m < 1)
                    atomicAdd(ab + (u * D_ + 4 * m + 2) * NN, (float)tv.y);
            }
        }
    }
}

// Gather (R10/R12 proven form): out[b,q,c] = sum_w A[b,w,p]*x2[b,c,p].
// Block = 32 q x 8 w-groups (256 thr), 1024 blocks. 21 c-accumulators in
// registers; LDS reduce over 8 planes; contiguous store.
#define GQ 32
#define RSTR 22
__global__ __launch_bounds__(256, 4) void rwn_gather(
    const float* __restrict__ Aarr,  // [B,W,NN]
    const float* __restrict__ x2,    // [B,C,NN]
    float* __restrict__ out)         // [B,NN,C]
{
    __shared__ float red[8 * GQ * RSTR];   // 22528 B

    const int q0 = blockIdx.x * GQ;
    const int b  = blockIdx.y;
    const int tid = threadIdx.x;
    const int qh = tid & (GQ - 1);
    const int wg = tid >> 5;
    const int q = q0 + qh;
    const int i = q >> 7, j = q & (N_ - 1);

    const float* Ab = Aarr + (size_t)b * W_ * NN;
    const float* xb = x2 + (size_t)b * C_ * NN;

    float acc[C_];
    #pragma unroll
    for (int c = 0; c < C_; ++c) acc[c] = 0.f;

    if (wg < D_) {
        const int pi = i - (wg - R_);
        const int cpi = pi < 0 ? 0 : (pi > N_ - 1 ? N_ - 1 : pi);
        const float rv = (pi >= 0 && pi < N_) ? 1.f : 0.f;
        const float* Aw = Ab + (size_t)wg * D_ * NN;
        #pragma unroll
        for (int v = 0; v < D_; ++v) {
            const int pj = j - (v - R_);
            const int cpj = pj < 0 ? 0 : (pj > N_ - 1 ? N_ - 1 : pj);
            const float vv = (pj >= 0 && pj < N_) ? rv : 0.f;
            const int p = cpi * N_ + cpj;
            const float a = vv * Aw[(size_t)v * NN + p];
            #pragma unroll
            for (int c = 0; c < C_; ++c)
                acc[c] += a * xb[(size_t)c * NN + p];
        }
    }

    float* rbase = red + (wg * GQ + qh) * RSTR;
    #pragma unroll
    for (int c = 0; c < C_; ++c) rbase[c] = acc[c];
    __syncthreads();

    float* ob = out + ((size_t)b * NN + q0) * C_;
    for (int e = tid; e < GQ * C_; e += 256) {
        const int qq = e / C_, cc = e - qq * C_;
        const int a = qq * RSTR + cc;
        float s = 0.f;
        #pragma unroll
        for (int pl = 0; pl < 8; ++pl)
            s += red[pl * GQ * RSTR + a];
        ob[e] = s;
    }
}

extern "C" void kernel_launch(void* const* d_in, const int* in_sizes, int n_in,
                              void* d_out, int out_size, void* d_ws, size_t ws_size,
                              hipStream_t stream) {
    const float* feats = (const float*)d_in[0];   // [B,K,N,N]
    const float* x2    = (const float*)d_in[1];   // [B,C,NN]
    const int*   mask  = (const int*)d_in[2];     // [B,N,N]
    const float* cp    = (const float*)d_in[3];   // [K]
    float* out = (float*)d_out;

    float* Aarr = (float*)d_ws;                   // [B,W,NN] fp32
    const size_t Abytes = (size_t)B_ * W_ * NN * sizeof(float);

    (void)hipMemsetAsync(Aarr, 0, Abytes, stream);

    dim3 gridA(64, KC, B_);
    rwn_affinity<<<gridA, 256, 0, stream>>>(feats, mask, cp, Aarr);

    dim3 gridG(NN / GQ, B_);
    rwn_gather<<<gridG, 256, 0, stream>>>(Aarr, x2, out);
}